// Round 1
// baseline (908.877 us; speedup 1.0000x reference)
//
#include <hip/hip_runtime.h>

// ---------------- CSR build ----------------

__global__ void k_hist(const int* __restrict__ dst, int E, int* __restrict__ hist) {
    int e = blockIdx.x * blockDim.x + threadIdx.x;
    if (e < E) atomicAdd(&hist[dst[e]], 1);
}

__global__ void k_dinv(const int* __restrict__ hist, int N, float* __restrict__ dinv) {
    int i = blockIdx.x * blockDim.x + threadIdx.x;
    if (i < N) dinv[i] = rsqrtf((float)(hist[i] + 1));  // +1 self-loop; deg>0 always
}

__global__ void k_blocksum(const int* __restrict__ hist, int N, int* __restrict__ bsums) {
    __shared__ int s[256];
    int t = threadIdx.x;
    int i = blockIdx.x * 256 + t;
    s[t] = (i < N) ? hist[i] : 0;
    __syncthreads();
    for (int off = 128; off > 0; off >>= 1) {
        if (t < off) s[t] += s[t + off];
        __syncthreads();
    }
    if (t == 0) bsums[blockIdx.x] = s[0];
}

// single block, 512 threads; nb <= 512
__global__ void k_scan_bsums(int* bsums, int nb) {
    __shared__ int s[2][512];
    int t = threadIdx.x;
    int v = (t < nb) ? bsums[t] : 0;
    int p = 0;
    s[0][t] = v;
    __syncthreads();
    for (int off = 1; off < 512; off <<= 1) {
        s[p ^ 1][t] = s[p][t] + ((t >= off) ? s[p][t - off] : 0);
        p ^= 1;
        __syncthreads();
    }
    if (t < nb) bsums[t] = s[p][t] - v;  // exclusive
}

__global__ void k_rowstart(const int* __restrict__ hist, const int* __restrict__ bsums,
                           int N, int* __restrict__ rowStart, int* __restrict__ cur) {
    __shared__ int s[2][256];
    int t = threadIdx.x;
    int i = blockIdx.x * 256 + t;
    int v = (i < N) ? hist[i] : 0;
    int p = 0;
    s[0][t] = v;
    __syncthreads();
    for (int off = 1; off < 256; off <<= 1) {
        s[p ^ 1][t] = s[p][t] + ((t >= off) ? s[p][t - off] : 0);
        p ^= 1;
        __syncthreads();
    }
    if (i < N) {
        int r = bsums[blockIdx.x] + s[p][t] - v;
        rowStart[i] = r;
        cur[i] = r;
    }
}

__global__ void k_scatter(const int* __restrict__ src, const int* __restrict__ dst, int E,
                          int* __restrict__ cur, int* __restrict__ csr_src) {
    int e = blockIdx.x * blockDim.x + threadIdx.x;
    if (e < E) {
        int pos = atomicAdd(&cur[dst[e]], 1);
        csr_src[pos] = src[e];
    }
}

// ---------------- GEMM1: h1 = X @ W1  (X [N,512] f32, W1 [512,16]) ----------------
// 256 rows/block, k staged in 16 chunks of 32 through LDS (pad 36 -> max 2-way bank
// conflicts on ds_read_b128 = free). W1 reads are wave-uniform -> s_load broadcast.

__global__ __launch_bounds__(256) void k_gemm1(const float* __restrict__ x,
                                               const float* __restrict__ W1,
                                               int N, float* __restrict__ h1) {
    __shared__ float xs[256 * 36];  // 36 KB
    const int t = threadIdx.x;
    const int R0 = blockIdx.x * 256;

    float acc[16];
#pragma unroll
    for (int c = 0; c < 16; ++c) acc[c] = 0.0f;

    for (int ch = 0; ch < 16; ++ch) {
        __syncthreads();
        // stage 256 rows x 32 k-values, coalesced float4
#pragma unroll
        for (int it = 0; it < 8; ++it) {
            int f = t + 256 * it;
            int r = f >> 3, j4 = f & 7;
            int row = R0 + r;
            float4 v = make_float4(0.f, 0.f, 0.f, 0.f);
            if (row < N) v = *(const float4*)(x + (size_t)row * 512 + ch * 32 + j4 * 4);
            *(float4*)(xs + r * 36 + j4 * 4) = v;
        }
        __syncthreads();
        const float4* xr = (const float4*)(xs + t * 36);
#pragma unroll
        for (int j4 = 0; j4 < 8; ++j4) {
            float4 xv = xr[j4];
            float xe[4] = {xv.x, xv.y, xv.z, xv.w};
            int k = ch * 32 + j4 * 4;
#pragma unroll
            for (int d = 0; d < 4; ++d) {
                const float* w = W1 + (k + d) * 16;  // wave-uniform -> scalar loads
#pragma unroll
                for (int c = 0; c < 16; ++c) acc[c] = fmaf(xe[d], w[c], acc[c]);
            }
        }
    }

    int row = R0 + t;
    if (row < N) {
        float4* o = (float4*)(h1 + (size_t)row * 16);
        o[0] = make_float4(acc[0], acc[1], acc[2], acc[3]);
        o[1] = make_float4(acc[4], acc[5], acc[6], acc[7]);
        o[2] = make_float4(acc[8], acc[9], acc[10], acc[11]);
        o[3] = make_float4(acc[12], acc[13], acc[14], acc[15]);
    }
}

// ---------------- Aggregation layer 1: relu1 = relu(A_norm @ h1 + b1) ----------------
// 16 threads per node (one per feature); self-loop + bias folded into init.

__global__ void k_gather1(const float* __restrict__ h1, const int* __restrict__ csr_src,
                          const int* __restrict__ rowStart, const int* __restrict__ hist,
                          const float* __restrict__ dinv, const float* __restrict__ b1,
                          int N, float* __restrict__ relu1) {
    int g = blockIdx.x * blockDim.x + threadIdx.x;
    int i = g >> 4, c = g & 15;
    if (i >= N) return;
    float di = dinv[i];
    float v = b1[c] + h1[(size_t)i * 16 + c] * di * di;  // self-loop norm = dinv^2
    int e0 = rowStart[i], e1 = e0 + hist[i];
    for (int e = e0; e < e1; ++e) {
        int s = csr_src[e];
        v += h1[(size_t)s * 16 + c] * dinv[s] * di;
    }
    relu1[(size_t)i * 16 + c] = fmaxf(v, 0.0f);
}

// ---------------- h2 = relu1 @ W2  (W2 [16,7]) ----------------

__global__ void k_h2(const float* __restrict__ relu1, const float* __restrict__ W2,
                     int N, float* __restrict__ h2) {
    int i = blockIdx.x * blockDim.x + threadIdx.x;
    if (i >= N) return;
    float r[16];
#pragma unroll
    for (int q = 0; q < 4; ++q) {
        float4 v = *(const float4*)(relu1 + (size_t)i * 16 + q * 4);
        r[q * 4 + 0] = v.x; r[q * 4 + 1] = v.y; r[q * 4 + 2] = v.z; r[q * 4 + 3] = v.w;
    }
#pragma unroll
    for (int c2 = 0; c2 < 7; ++c2) {
        float a = 0.0f;
#pragma unroll
        for (int c = 0; c < 16; ++c) a = fmaf(r[c], W2[c * 7 + c2], a);
        h2[(size_t)i * 7 + c2] = a;
    }
}

// ---------------- Aggregation layer 2: out = A_norm @ h2 + b2 ----------------
// 8 threads per node (7 active).

__global__ void k_gather2(const float* __restrict__ h2, const int* __restrict__ csr_src,
                          const int* __restrict__ rowStart, const int* __restrict__ hist,
                          const float* __restrict__ dinv, const float* __restrict__ b2,
                          int N, float* __restrict__ out) {
    int g = blockIdx.x * blockDim.x + threadIdx.x;
    int i = g >> 3, c = g & 7;
    if (i >= N || c >= 7) return;
    float di = dinv[i];
    float v = b2[c] + h2[(size_t)i * 7 + c] * di * di;
    int e0 = rowStart[i], e1 = e0 + hist[i];
    for (int e = e0; e < e1; ++e) {
        int s = csr_src[e];
        v += h2[(size_t)s * 7 + c] * dinv[s] * di;
    }
    out[(size_t)i * 7 + c] = v;
}

// ---------------- launch ----------------

extern "C" void kernel_launch(void* const* d_in, const int* in_sizes, int n_in,
                              void* d_out, int out_size, void* d_ws, size_t ws_size,
                              hipStream_t stream) {
    const float* x  = (const float*)d_in[0];
    const int*   ei = (const int*)d_in[1];
    const float* W1 = (const float*)d_in[2];
    const float* b1 = (const float*)d_in[3];
    const float* W2 = (const float*)d_in[4];
    const float* b2 = (const float*)d_in[5];
    float* out = (float*)d_out;

    const int N = in_sizes[0] / 512;
    const int E = in_sizes[1] / 2;
    const int* src = ei;       // edge_index[0]
    const int* dst = ei + E;   // edge_index[1]

    char* ws = (char*)d_ws;
    auto alloc = [&](size_t bytes) {
        char* p = ws;
        ws += (bytes + 511) & ~(size_t)511;
        return p;
    };
    int*   hist     = (int*)alloc((size_t)N * 4);
    float* dinv     = (float*)alloc((size_t)N * 4);
    int*   rowStart = (int*)alloc((size_t)N * 4);
    int*   cur      = (int*)alloc((size_t)N * 4);
    int*   bsums    = (int*)alloc(4096);
    int*   csr_src  = (int*)alloc((size_t)E * 4);
    float* h1       = (float*)alloc((size_t)N * 16 * 4);
    float* relu1    = (float*)alloc((size_t)N * 16 * 4);
    float* h2       = (float*)alloc((size_t)N * 7 * 4);

    const int nb  = (N + 255) / 256;          // 391
    const int neb = (E + 255) / 256;          // 12500

    hipMemsetAsync(hist, 0, (size_t)N * 4, stream);
    k_hist<<<neb, 256, 0, stream>>>(dst, E, hist);
    k_dinv<<<nb, 256, 0, stream>>>(hist, N, dinv);
    k_blocksum<<<nb, 256, 0, stream>>>(hist, N, bsums);
    k_scan_bsums<<<1, 512, 0, stream>>>(bsums, nb);
    k_rowstart<<<nb, 256, 0, stream>>>(hist, bsums, N, rowStart, cur);
    k_scatter<<<neb, 256, 0, stream>>>(src, dst, E, cur, csr_src);
    k_gemm1<<<nb, 256, 0, stream>>>(x, W1, N, h1);
    k_gather1<<<(N * 16 + 255) / 256, 256, 0, stream>>>(h1, csr_src, rowStart, hist, dinv, b1, N, relu1);
    k_h2<<<nb, 256, 0, stream>>>(relu1, W2, N, h2);
    k_gather2<<<(N * 8 + 255) / 256, 256, 0, stream>>>(h2, csr_src, rowStart, hist, dinv, b2, N, out);
}

// Round 3
// 627.783 us; speedup vs baseline: 1.4478x; 1.4478x over previous
//
#include <hip/hip_runtime.h>

#define CHUNK 8192           // edges per block in coarse pass
#define BMAX 512             // max coarse buckets (N/256 <= 512)

// ---------------- coarse bucket histogram ----------------
// Each block counts its CHUNK of edges into B buckets (dst>>8) in LDS, then
// reserves space per bucket via one global atomicAdd (return value = this
// block's base within the bucket).

__global__ __launch_bounds__(256) void k_coarse_hist(const int* __restrict__ dst, int E,
                                                     int* __restrict__ bc,
                                                     int* __restrict__ blockBase, int B) {
    __shared__ int cnt[BMAX];
    int t = threadIdx.x;
    cnt[t] = 0; cnt[t + 256] = 0;
    __syncthreads();
    int e0 = blockIdx.x * CHUNK;
#pragma unroll
    for (int it = 0; it < CHUNK / 256; ++it) {
        int e = e0 + it * 256 + t;
        if (e < E) atomicAdd(&cnt[dst[e] >> 8], 1);
    }
    __syncthreads();
    for (int b = t; b < B; b += 256) {
        int c = cnt[b];
        if (c > 0) blockBase[(size_t)blockIdx.x * B + b] = atomicAdd(&bc[b], c);
    }
}

// single block, 512 threads; exclusive scan in place (n <= 512)
__global__ void k_scan_bsums(int* bsums, int nb) {
    __shared__ int s[2][512];
    int t = threadIdx.x;
    int v = (t < nb) ? bsums[t] : 0;
    int p = 0;
    s[0][t] = v;
    __syncthreads();
    for (int off = 1; off < 512; off <<= 1) {
        s[p ^ 1][t] = s[p][t] + ((t >= off) ? s[p][t - off] : 0);
        p ^= 1;
        __syncthreads();
    }
    if (t < nb) bsums[t] = s[p][t] - v;  // exclusive
}

// ---------------- coarse scatter ----------------
// Re-read chunk, rank within (block,bucket) via LDS counters, write packed
// word (localdst<<24 | src) at bucketBase + blockBase + rank. Writes are
// sequential runs per bucket region.

__global__ __launch_bounds__(256) void k_coarse_scatter(const int* __restrict__ src,
                                                        const int* __restrict__ dst, int E,
                                                        const int* __restrict__ bucketBase,
                                                        const int* __restrict__ blockBase, int B,
                                                        unsigned int* __restrict__ ebuf) {
    __shared__ int run[BMAX];
    int t = threadIdx.x;
    run[t] = 0; run[t + 256] = 0;
    __syncthreads();
    int e0 = blockIdx.x * CHUNK;
#pragma unroll
    for (int it = 0; it < CHUNK / 256; ++it) {
        int e = e0 + it * 256 + t;
        if (e < E) {
            int d = dst[e];
            int b = d >> 8;
            int rank = atomicAdd(&run[b], 1);
            int pos = bucketBase[b] + blockBase[(size_t)blockIdx.x * B + b] + rank;
            ebuf[pos] = ((unsigned int)(d & 255) << 24) | (unsigned int)src[e];
        }
    }
}

// ---------------- per-node degree histogram from bucketed edges ----------------
// One block per bucket: LDS-atomic count over 256 local nodes, contiguous store.

__global__ __launch_bounds__(256) void k_bucket_hist(const unsigned int* __restrict__ ebuf,
                                                     const int* __restrict__ bucketBase,
                                                     int E, int N, int B,
                                                     int* __restrict__ hist) {
    __shared__ int cnt[256];
    int t = threadIdx.x;
    int b = blockIdx.x;
    cnt[t] = 0;
    __syncthreads();
    int e0 = bucketBase[b];
    int e1 = (b + 1 < B) ? bucketBase[b + 1] : E;
    for (int e = e0 + t; e < e1; e += 256) atomicAdd(&cnt[ebuf[e] >> 24], 1);
    __syncthreads();
    int node = b * 256 + t;
    if (node < N) hist[node] = cnt[t];
}

__global__ void k_dinv(const int* __restrict__ hist, int N, float* __restrict__ dinv) {
    int i = blockIdx.x * blockDim.x + threadIdx.x;
    if (i < N) dinv[i] = rsqrtf((float)(hist[i] + 1));  // +1 self-loop
}

__global__ void k_blocksum(const int* __restrict__ hist, int N, int* __restrict__ bsums) {
    __shared__ int s[256];
    int t = threadIdx.x;
    int i = blockIdx.x * 256 + t;
    s[t] = (i < N) ? hist[i] : 0;
    __syncthreads();
    for (int off = 128; off > 0; off >>= 1) {
        if (t < off) s[t] += s[t + off];
        __syncthreads();
    }
    if (t == 0) bsums[blockIdx.x] = s[0];
}

__global__ void k_rowstart(const int* __restrict__ hist, const int* __restrict__ bsums,
                           int N, int* __restrict__ rowStart) {
    __shared__ int s[2][256];
    int t = threadIdx.x;
    int i = blockIdx.x * 256 + t;
    int v = (i < N) ? hist[i] : 0;
    int p = 0;
    s[0][t] = v;
    __syncthreads();
    for (int off = 1; off < 256; off <<= 1) {
        s[p ^ 1][t] = s[p][t] + ((t >= off) ? s[p][t - off] : 0);
        p ^= 1;
        __syncthreads();
    }
    if (i < N) rowStart[i] = bsums[blockIdx.x] + s[p][t] - v;
}

// ---------------- fine scatter: bucket -> CSR ----------------
// One block per bucket; CSR position from LDS counters seeded with rowStart.
// Writes land in the bucket's contiguous ~32KB CSR span.

__global__ __launch_bounds__(256) void k_fine_scatter(const unsigned int* __restrict__ ebuf,
                                                      const int* __restrict__ bucketBase,
                                                      const int* __restrict__ rowStart,
                                                      int E, int N, int B,
                                                      int* __restrict__ csr_src) {
    __shared__ int cnt[256];
    int t = threadIdx.x;
    int b = blockIdx.x;
    int node = b * 256 + t;
    cnt[t] = (node < N) ? rowStart[node] : 0;
    __syncthreads();
    int e0 = bucketBase[b];
    int e1 = (b + 1 < B) ? bucketBase[b + 1] : E;
    for (int e = e0 + t; e < e1; e += 256) {
        unsigned int w = ebuf[e];
        int pos = atomicAdd(&cnt[w >> 24], 1);
        csr_src[pos] = (int)(w & 0xFFFFFFu);
    }
}

// ---------------- GEMM1: h1 = X @ W1  (X [N,512] f32, W1 [512,16]) ----------------

__global__ __launch_bounds__(256) void k_gemm1(const float* __restrict__ x,
                                               const float* __restrict__ W1,
                                               int N, float* __restrict__ h1) {
    __shared__ float xs[256 * 36];  // 36 KB, +4 pad -> max 2-way bank conflict (free)
    const int t = threadIdx.x;
    const int R0 = blockIdx.x * 256;

    float acc[16];
#pragma unroll
    for (int c = 0; c < 16; ++c) acc[c] = 0.0f;

    for (int ch = 0; ch < 16; ++ch) {
        __syncthreads();
#pragma unroll
        for (int it = 0; it < 8; ++it) {
            int f = t + 256 * it;
            int r = f >> 3, j4 = f & 7;
            int row = R0 + r;
            float4 v = make_float4(0.f, 0.f, 0.f, 0.f);
            if (row < N) v = *(const float4*)(x + (size_t)row * 512 + ch * 32 + j4 * 4);
            *(float4*)(xs + r * 36 + j4 * 4) = v;
        }
        __syncthreads();
        const float4* xr = (const float4*)(xs + t * 36);
#pragma unroll
        for (int j4 = 0; j4 < 8; ++j4) {
            float4 xv = xr[j4];
            float xe[4] = {xv.x, xv.y, xv.z, xv.w};
            int k = ch * 32 + j4 * 4;
#pragma unroll
            for (int d = 0; d < 4; ++d) {
                const float* w = W1 + (k + d) * 16;  // wave-uniform -> scalar loads
#pragma unroll
                for (int c = 0; c < 16; ++c) acc[c] = fmaf(xe[d], w[c], acc[c]);
            }
        }
    }

    int row = R0 + t;
    if (row < N) {
        float4* o = (float4*)(h1 + (size_t)row * 16);
        o[0] = make_float4(acc[0], acc[1], acc[2], acc[3]);
        o[1] = make_float4(acc[4], acc[5], acc[6], acc[7]);
        o[2] = make_float4(acc[8], acc[9], acc[10], acc[11]);
        o[3] = make_float4(acc[12], acc[13], acc[14], acc[15]);
    }
}

// ---------------- Aggregation layer 1: relu1 = relu(A_norm @ h1 + b1) ----------------

__global__ void k_gather1(const float* __restrict__ h1, const int* __restrict__ csr_src,
                          const int* __restrict__ rowStart, const int* __restrict__ hist,
                          const float* __restrict__ dinv, const float* __restrict__ b1,
                          int N, float* __restrict__ relu1) {
    int g = blockIdx.x * blockDim.x + threadIdx.x;
    int i = g >> 4, c = g & 15;
    if (i >= N) return;
    float di = dinv[i];
    float v = b1[c] + h1[(size_t)i * 16 + c] * di * di;  // self-loop norm = dinv^2
    int e0 = rowStart[i], e1 = e0 + hist[i];
    for (int e = e0; e < e1; ++e) {
        int s = csr_src[e];
        v += h1[(size_t)s * 16 + c] * dinv[s] * di;
    }
    relu1[(size_t)i * 16 + c] = fmaxf(v, 0.0f);
}

// ---------------- h2 = relu1 @ W2  (W2 [16,7]) ----------------

__global__ void k_h2(const float* __restrict__ relu1, const float* __restrict__ W2,
                     int N, float* __restrict__ h2) {
    int i = blockIdx.x * blockDim.x + threadIdx.x;
    if (i >= N) return;
    float r[16];
#pragma unroll
    for (int q = 0; q < 4; ++q) {
        float4 v = *(const float4*)(relu1 + (size_t)i * 16 + q * 4);
        r[q * 4 + 0] = v.x; r[q * 4 + 1] = v.y; r[q * 4 + 2] = v.z; r[q * 4 + 3] = v.w;
    }
#pragma unroll
    for (int c2 = 0; c2 < 7; ++c2) {
        float a = 0.0f;
#pragma unroll
        for (int c = 0; c < 16; ++c) a = fmaf(r[c], W2[c * 7 + c2], a);
        h2[(size_t)i * 7 + c2] = a;
    }
}

// ---------------- Aggregation layer 2: out = A_norm @ h2 + b2 ----------------

__global__ void k_gather2(const float* __restrict__ h2, const int* __restrict__ csr_src,
                          const int* __restrict__ rowStart, const int* __restrict__ hist,
                          const float* __restrict__ dinv, const float* __restrict__ b2,
                          int N, float* __restrict__ out) {
    int g = blockIdx.x * blockDim.x + threadIdx.x;
    int i = g >> 3, c = g & 7;
    if (i >= N || c >= 7) return;
    float di = dinv[i];
    float v = b2[c] + h2[(size_t)i * 7 + c] * di * di;
    int e0 = rowStart[i], e1 = e0 + hist[i];
    for (int e = e0; e < e1; ++e) {
        int s = csr_src[e];
        v += h2[(size_t)s * 7 + c] * dinv[s] * di;
    }
    out[(size_t)i * 7 + c] = v;
}

// ---------------- launch ----------------

extern "C" void kernel_launch(void* const* d_in, const int* in_sizes, int n_in,
                              void* d_out, int out_size, void* d_ws, size_t ws_size,
                              hipStream_t stream) {
    const float* x  = (const float*)d_in[0];
    const int*   ei = (const int*)d_in[1];
    const float* W1 = (const float*)d_in[2];
    const float* b1 = (const float*)d_in[3];
    const float* W2 = (const float*)d_in[4];
    const float* b2 = (const float*)d_in[5];
    float* out = (float*)d_out;

    const int N = in_sizes[0] / 512;
    const int E = in_sizes[1] / 2;
    const int* src = ei;       // edge_index[0]
    const int* dst = ei + E;   // edge_index[1]

    const int nb  = (N + 255) / 256;           // 391 (node blocks == coarse buckets)
    const int B   = nb;
    const int nbA = (E + CHUNK - 1) / CHUNK;   // 391 coarse blocks

    char* ws = (char*)d_ws;
    auto alloc = [&](size_t bytes) {
        char* p = ws;
        ws += (bytes + 511) & ~(size_t)511;
        return p;
    };
    // persistent region
    int*   hist      = (int*)alloc((size_t)N * 4);
    float* dinv      = (float*)alloc((size_t)N * 4);
    int*   rowStart  = (int*)alloc((size_t)N * 4);
    int*   bsums     = (int*)alloc(4096);
    int*   bc        = (int*)alloc((size_t)(B + 1) * 4);
    int*   blockBase = (int*)alloc((size_t)nbA * B * 4);
    int*   csr_src   = (int*)alloc((size_t)E * 4);
    // overlapped region: ebuf (dead after fine_scatter) unions with h1/relu1/h2
    size_t featBytes = (size_t)N * 16 * 4 * 2 + (size_t)N * 7 * 4;
    size_t ebufBytes = (size_t)E * 4;
    char* regB = alloc(featBytes > ebufBytes ? featBytes : ebufBytes);
    unsigned int* ebuf = (unsigned int*)regB;
    float* h1    = (float*)regB;
    float* relu1 = h1 + (size_t)N * 16;
    float* h2    = relu1 + (size_t)N * 16;

    hipMemsetAsync(bc, 0, (size_t)B * 4, stream);
    k_coarse_hist<<<nbA, 256, 0, stream>>>(dst, E, bc, blockBase, B);
    k_scan_bsums<<<1, 512, 0, stream>>>(bc, B);                       // bc -> bucketBase
    k_coarse_scatter<<<nbA, 256, 0, stream>>>(src, dst, E, bc, blockBase, B, ebuf);
    k_bucket_hist<<<B, 256, 0, stream>>>(ebuf, bc, E, N, B, hist);
    k_dinv<<<nb, 256, 0, stream>>>(hist, N, dinv);
    k_blocksum<<<nb, 256, 0, stream>>>(hist, N, bsums);
    k_scan_bsums<<<1, 512, 0, stream>>>(bsums, nb);
    k_rowstart<<<nb, 256, 0, stream>>>(hist, bsums, N, rowStart);
    k_fine_scatter<<<B, 256, 0, stream>>>(ebuf, bc, rowStart, E, N, B, csr_src);
    k_gemm1<<<nb, 256, 0, stream>>>(x, W1, N, h1);
    k_gather1<<<(N * 16 + 255) / 256, 256, 0, stream>>>(h1, csr_src, rowStart, hist, dinv, b1, N, relu1);
    k_h2<<<nb, 256, 0, stream>>>(relu1, W2, N, h2);
    k_gather2<<<(N * 8 + 255) / 256, 256, 0, stream>>>(h2, csr_src, rowStart, hist, dinv, b2, N, out);
}